// Round 5
// baseline (765.749 us; speedup 1.0000x reference)
//
#include <hip/hip_runtime.h>
#include <float.h>
#include <stdint.h>

#define D_DIM 512

typedef __attribute__((ext_vector_type(8))) short bf16x8;
typedef __attribute__((ext_vector_type(4))) float f32x4;

// async global->LDS, 16B per lane (linear LDS dest: wave base + lane*16)
#define GLD_LDS16(g, l)                                              \
    __builtin_amdgcn_global_load_lds(                                \
        (const __attribute__((address_space(1))) void*)(g),          \
        (__attribute__((address_space(3))) void*)(l), 16, 0, 0)

// round-half-up f32->bf16, pack two into one u32
__device__ __forceinline__ uint32_t pk_bf16(float a, float b) {
    uint32_t ua = __builtin_bit_cast(uint32_t, a) + 0x8000u;
    uint32_t ub = __builtin_bit_cast(uint32_t, b) + 0x8000u;
    return (ua >> 16) | (ub & 0xFFFF0000u);
}

// ---------------------------------------------------------------------------
// Per-row: r[row] = 1/max(||X[row]||,eps); Xb[row,:] = bf16(X[row,:] * r).
// ---------------------------------------------------------------------------
__global__ __launch_bounds__(256) void convert_norm_kernel(
        const float* __restrict__ X, unsigned short* __restrict__ Xb,
        float* __restrict__ r, int R) {
    int row = blockIdx.x * 4 + (threadIdx.x >> 6);
    if (row >= R) return;
    int lane = threadIdx.x & 63;
    const float* x = X + (size_t)row * D_DIM + lane * 8;
    float4 f0 = *(const float4*)(x);
    float4 f1 = *(const float4*)(x + 4);
    float s = f0.x*f0.x + f0.y*f0.y + f0.z*f0.z + f0.w*f0.w
            + f1.x*f1.x + f1.y*f1.y + f1.z*f1.z + f1.w*f1.w;
#pragma unroll
    for (int off = 32; off; off >>= 1) s += __shfl_xor(s, off);
    float rv = 1.0f / fmaxf(sqrtf(s), 1e-12f);
    if (lane == 0) r[row] = rv;
    uint4 w;
    w.x = pk_bf16(f0.x * rv, f0.y * rv);
    w.y = pk_bf16(f0.z * rv, f0.w * rv);
    w.z = pk_bf16(f1.x * rv, f1.y * rv);
    w.w = pk_bf16(f1.z * rv, f1.w * rv);
    *(uint4*)(Xb + (size_t)row * D_DIM + lane * 8) = w;
}

// ---------------------------------------------------------------------------
// bf16 GEMM, double-buffered 2-phase pipeline (T3-minimum + T5):
//   iter t: issue STAGE(t+1) -> vmcnt(8) -> s_barrier -> ds_read+MFMA(t)
//           -> s_barrier.  Next-tile loads fly under current MFMA phase.
// 128x128 tile, 4 waves, 4x4 frags mfma_f32_16x16x32_bf16, BK=64.
// FUSE epilogue: LDS-transpose tile (aliases staging LDS), per-row top-4
// per 128-col tile -> part.
// ---------------------------------------------------------------------------
template <bool FUSE>
__global__ __launch_bounds__(256) void gemm_lds_bf16(
        const unsigned short* __restrict__ Zb,
        const unsigned short* __restrict__ Pb,
        float* __restrict__ sim, uint2* __restrict__ part, int Pn) {
    __shared__ __align__(16) unsigned char SH[65536];
    uint4* S = (uint4*)SH;   // dbuf: [cur*2048 + (A:0..1023 | B:1024..2047)]

    int bi = blockIdx.x;
    int mb, nb;
    if (gridDim.x == 16384) {            // XCD band mapping (B=8192,P=32768)
        int xcd = bi & 7;
        int r = bi >> 3;
        mb = xcd * 8 + (r & 7);          // 0..63
        nb = r >> 3;                     // 0..255
    } else {
        nb = bi % (Pn / 128);
        mb = bi / (Pn / 128);
    }
    const int bm = mb * 128, bn = nb * 128;

    const int tid = threadIdx.x;
    const int lane = tid & 63;
    const int wid = tid >> 6;
    const int wr = wid >> 1, wc = wid & 1;
    const int ln15 = lane & 15, hi = lane >> 4;

    const unsigned short* gA[4];
    const unsigned short* gB[4];
    int ldsIdx[4];
#pragma unroll
    for (int q = 0; q < 4; ++q) {
        int flat = q * 256 + tid;        // 16B-chunk id: row*8 + c
        int row = flat >> 3;
        int c = flat & 7;
        int cg = c ^ (row & 7);          // pre-swizzled global chunk
        gA[q] = Zb + (size_t)(bm + row) * D_DIM + cg * 8;
        gB[q] = Pb + (size_t)(bn + row) * D_DIM + cg * 8;
        ldsIdx[q] = flat;
    }

    f32x4 acc[4][4] = {};

    // prologue: stage tile 0 into buffer 0
#pragma unroll
    for (int q = 0; q < 4; ++q) {
        GLD_LDS16(gA[q], &S[ldsIdx[q]]);
        GLD_LDS16(gB[q], &S[1024 + ldsIdx[q]]);
        gA[q] += 64;
        gB[q] += 64;
    }

    int cur = 0;
#pragma unroll 1
    for (int s8 = 0; s8 < 8; ++s8) {
        const int nxt = cur ^ 1;
        if (s8 < 7) {
            // issue next-tile loads; they stay in flight through this MFMA phase
#pragma unroll
            for (int q = 0; q < 4; ++q) {
                GLD_LDS16(gA[q], &S[nxt * 2048 + ldsIdx[q]]);
                GLD_LDS16(gB[q], &S[nxt * 2048 + 1024 + ldsIdx[q]]);
                gA[q] += 64;
                gB[q] += 64;
            }
            asm volatile("s_waitcnt vmcnt(8)" ::: "memory");  // tile-t landed
        } else {
            asm volatile("s_waitcnt vmcnt(0)" ::: "memory");
        }
        __builtin_amdgcn_s_barrier();
        __builtin_amdgcn_sched_barrier(0);

        const int sb = cur * 2048;
        __builtin_amdgcn_s_setprio(1);
#pragma unroll
        for (int kk = 0; kk < 2; ++kk) {
            bf16x8 av[4], bv[4];
            const int kch = kk * 4 + hi;
#pragma unroll
            for (int t = 0; t < 4; ++t) {
                int arow = wr * 64 + t * 16 + ln15;
                av[t] = __builtin_bit_cast(bf16x8,
                        S[sb + arow * 8 + (kch ^ (arow & 7))]);
                int brow = wc * 64 + t * 16 + ln15;
                bv[t] = __builtin_bit_cast(bf16x8,
                        S[sb + 1024 + brow * 8 + (kch ^ (brow & 7))]);
            }
#pragma unroll
            for (int i = 0; i < 4; ++i)
#pragma unroll
                for (int j = 0; j < 4; ++j)
                    acc[i][j] = __builtin_amdgcn_mfma_f32_16x16x32_bf16(
                        av[i], bv[j], acc[i][j], 0, 0, 0);
        }
        __builtin_amdgcn_s_setprio(0);
        __builtin_amdgcn_sched_barrier(0);
        __builtin_amdgcn_s_barrier();     // safe to overwrite buf[cur]
        cur = nxt;
    }

    // sim write: C/D layout col=lane&15, row=(lane>>4)*4+reg
#pragma unroll
    for (int i = 0; i < 4; ++i) {
#pragma unroll
        for (int rr = 0; rr < 4; ++rr) {
            int row = bm + wr * 64 + i * 16 + hi * 4 + rr;
#pragma unroll
            for (int j = 0; j < 4; ++j) {
                int col = bn + wc * 64 + j * 16 + ln15;
                sim[(size_t)row * Pn + col] = acc[i][j][rr];
            }
        }
    }

    if constexpr (FUSE) {
        float* T = (float*)SH;               // [128 cols][68] f32 = 34816 B
        uint2* M = (uint2*)(SH + 34816);     // [4 q][4 k][64 r] = 8192 B
        const int NB = Pn >> 7;
        const int r = tid & 63;
        const int q = wid;
#pragma unroll 1
        for (int hf = 0; hf < 2; ++hf) {
            __syncthreads();
            if (wr == hf) {
#pragma unroll
                for (int i = 0; i < 4; ++i)
#pragma unroll
                    for (int j = 0; j < 4; ++j)
                        *(f32x4*)&T[(wc * 64 + j * 16 + ln15) * 68 + i * 16 + hi * 4]
                            = acc[i][j];
            }
            __syncthreads();
            // scan: thread -> (row r, quarter q); top-4 of 32 cols
            float tv[4]; int ti[4];
#pragma unroll
            for (int k = 0; k < 4; ++k) { tv[k] = -FLT_MAX; ti[k] = 0x7FFFFFFF; }
#pragma unroll
            for (int c4 = 0; c4 < 32; c4 += 4) {
                float e0 = T[(q * 32 + c4 + 0) * 68 + r];
                float e1 = T[(q * 32 + c4 + 1) * 68 + r];
                float e2 = T[(q * 32 + c4 + 2) * 68 + r];
                float e3 = T[(q * 32 + c4 + 3) * 68 + r];
                float mg = fmaxf(fmaxf(e0, e1), fmaxf(e2, e3));
                if (mg > tv[3]) {   // rare-path gate: skip 4-elem insert chain
                    float ee[4] = {e0, e1, e2, e3};
#pragma unroll
                    for (int e = 0; e < 4; ++e) {
                        float val = ee[e];
                        if (val > tv[3]) {
                            int p = 3;
#pragma unroll
                            for (int j2 = 2; j2 >= 0; --j2)
                                if (val > tv[j2]) { tv[j2+1] = tv[j2]; ti[j2+1] = ti[j2]; p = j2; }
                            tv[p] = val; ti[p] = bn + q * 32 + c4 + e;
                        }
                    }
                }
            }
#pragma unroll
            for (int k = 0; k < 4; ++k)
                M[q * 256 + k * 64 + r] =
                    make_uint2(__builtin_bit_cast(uint32_t, tv[k]), (uint32_t)ti[k]);
            __syncthreads();
            if (tid < 64) {   // merge 4 quarters -> row top-4, write partials
                float fv[4]; int fi[4];
#pragma unroll
                for (int k = 0; k < 4; ++k) { fv[k] = -FLT_MAX; fi[k] = 0x7FFFFFFF; }
#pragma unroll
                for (int qq = 0; qq < 4; ++qq)
#pragma unroll
                    for (int k = 0; k < 4; ++k) {
                        uint2 u = M[qq * 256 + k * 64 + tid];
                        float val = __builtin_bit_cast(float, u.x);
                        if (val > fv[3]) {
                            int p = 3;
#pragma unroll
                            for (int j2 = 2; j2 >= 0; --j2)
                                if (val > fv[j2]) { fv[j2+1] = fv[j2]; fi[j2+1] = fi[j2]; p = j2; }
                            fv[p] = val; fi[p] = (int)u.y;
                        }
                    }
                size_t o = ((size_t)(bm + hf * 64 + tid) * NB + nb) * 4;
#pragma unroll
                for (int k = 0; k < 4; ++k)
                    part[o + k] =
                        make_uint2(__builtin_bit_cast(uint32_t, fv[k]), (uint32_t)fi[k]);
            }
        }
    }
}

// ---------------------------------------------------------------------------
// Reduce partial candidates (NB*4 per row) -> noisy top-8 -> exact f32
// rerank -> top-3. One wave per row.
// ---------------------------------------------------------------------------
__global__ __launch_bounds__(256) void topk_reduce(const uint2* __restrict__ part,
        const float* __restrict__ Z, const float* __restrict__ Pm,
        const float* __restrict__ rz, const float* __restrict__ rp,
        float* __restrict__ oidx, float* __restrict__ oval, int Pn) {
    int row = blockIdx.x * 4 + (threadIdx.x >> 6);
    int lane = threadIdx.x & 63;
    const int NB = Pn >> 7;
    const uint2* pr = part + (size_t)row * NB * 4;

    float v[8]; int ix[8];
#pragma unroll
    for (int j = 0; j < 8; ++j) { v[j] = -FLT_MAX; ix[j] = -1; }

    const int total = NB * 4;
    for (int c = lane; c < total; c += 64) {
        uint2 u = pr[c];
        float val = __builtin_bit_cast(float, u.x);
        if (val > v[7]) {
            int idx = (int)u.y;
            int pos = 7;
#pragma unroll
            for (int j = 6; j >= 0; --j) {
                if (val > v[j]) { v[j+1] = v[j]; ix[j+1] = ix[j]; pos = j; }
            }
            v[pos] = val; ix[pos] = idx;
        }
    }

    int cand[8];
#pragma unroll
    for (int k = 0; k < 8; ++k) {
        float bv = v[0]; int bi2 = ix[0];
#pragma unroll
        for (int off = 32; off; off >>= 1) {
            float ov = __shfl_xor(bv, off);
            int oi = __shfl_xor(bi2, off);
            if (ov > bv || (ov == bv && oi >= 0 && (unsigned)oi < (unsigned)bi2)) {
                bv = ov; bi2 = oi;
            }
        }
        cand[k] = bi2;
        if (bi2 == ix[0]) {
#pragma unroll
            for (int j = 0; j < 7; ++j) { v[j] = v[j+1]; ix[j] = ix[j+1]; }
            v[7] = -FLT_MAX; ix[7] = -1;
        }
    }

    // exact f32 recompute of the 8 candidate similarities
    float zv[8];
    const float* zrow = Z + (size_t)row * D_DIM + lane * 8;
#pragma unroll
    for (int j = 0; j < 8; ++j) zv[j] = zrow[j];
    float rzv = rz[row];

    float ex[8];
#pragma unroll
    for (int c = 0; c < 8; ++c) {
        int idx = cand[c];
        const float* prow = Pm + (size_t)idx * D_DIM + lane * 8;
        float s = 0.f;
#pragma unroll
        for (int j = 0; j < 8; ++j) s += zv[j] * prow[j];
#pragma unroll
        for (int off = 32; off; off >>= 1) s += __shfl_xor(s, off);
        ex[c] = s * rzv * rp[idx];
    }

    bool used[8] = {};
#pragma unroll
    for (int k = 0; k < 3; ++k) {
        float bv = -FLT_MAX; int bi2 = Pn; int bc = 0;
#pragma unroll
        for (int c = 0; c < 8; ++c) {
            if (!used[c] && (ex[c] > bv || (ex[c] == bv && cand[c] < bi2))) {
                bv = ex[c]; bi2 = cand[c]; bc = c;
            }
        }
        used[bc] = true;
        if (lane == 0) {
            oidx[(size_t)row * 3 + k] = (float)bi2;
            oval[(size_t)row * 3 + k] = bv;
        }
    }
}

// ---------------------------------------------------------------------------
// Fallbacks (smaller ws): topk over sim, f32-input reg-staging GEMM.
// ---------------------------------------------------------------------------
__global__ __launch_bounds__(256) void rnorm_kernel(const float* __restrict__ X,
                                                    float* __restrict__ r, int R) {
    int row = blockIdx.x * 4 + (threadIdx.x >> 6);
    if (row >= R) return;
    int lane = threadIdx.x & 63;
    const float* x = X + (size_t)row * D_DIM;
    float s = 0.f;
#pragma unroll
    for (int t = 0; t < 2; ++t) {
        float4 v = *(const float4*)(x + (t * 64 + lane) * 4);
        s += v.x * v.x + v.y * v.y + v.z * v.z + v.w * v.w;
    }
#pragma unroll
    for (int off = 32; off; off >>= 1) s += __shfl_xor(s, off);
    if (lane == 0) r[row] = 1.0f / fmaxf(sqrtf(s), 1e-12f);
}

__global__ __launch_bounds__(256, 2) void gemm_bf16_sim(const float* __restrict__ Z,
        const float* __restrict__ Pm, const float* __restrict__ rz,
        const float* __restrict__ rp, float* __restrict__ sim, int Pn) {
    __shared__ uint4 As16[1024];
    __shared__ uint4 Bs16[1024];
    int bi = blockIdx.x;
    int mb, nb;
    if (gridDim.x == 16384) {
        int xcd = bi & 7;
        int r = bi >> 3;
        mb = xcd * 8 + (r & 7);
        nb = r >> 3;
    } else {
        nb = bi % (Pn / 128);
        mb = bi / (Pn / 128);
    }
    const int bm = mb * 128, bn = nb * 128;
    const int tid = threadIdx.x;
    const int srow = tid >> 1;
    const int half = tid & 1;
    const float* aP = Z  + (size_t)(bm + srow) * D_DIM + half * 32;
    const float* bP = Pm + (size_t)(bn + srow) * D_DIM + half * 32;
    const int lane = tid & 63;
    const int wid = tid >> 6;
    const int wr = wid >> 1, wc = wid & 1;
    const int ln15 = lane & 15, hi = lane >> 4;
    f32x4 acc[4][4] = {};
    float4 f[8], g[8];
#pragma unroll
    for (int q = 0; q < 8; ++q) {
        f[q] = *(const float4*)(aP + q * 4);
        g[q] = *(const float4*)(bP + q * 4);
    }
#pragma unroll 1
    for (int s = 0; s < 8; ++s) {
#pragma unroll
        for (int q8 = 0; q8 < 4; ++q8) {
            uint4 wa, wb;
            wa.x = pk_bf16(f[2*q8].x,   f[2*q8].y);
            wa.y = pk_bf16(f[2*q8].z,   f[2*q8].w);
            wa.z = pk_bf16(f[2*q8+1].x, f[2*q8+1].y);
            wa.w = pk_bf16(f[2*q8+1].z, f[2*q8+1].w);
            wb.x = pk_bf16(g[2*q8].x,   g[2*q8].y);
            wb.y = pk_bf16(g[2*q8].z,   g[2*q8].w);
            wb.z = pk_bf16(g[2*q8+1].x, g[2*q8+1].y);
            wb.w = pk_bf16(g[2*q8+1].z, g[2*q8+1].w);
            int colByte = half * 64 + q8 * 16;
            int idx = srow * 8 + ((colByte ^ ((srow & 7) << 4)) >> 4);
            As16[idx] = wa;
            Bs16[idx] = wb;
        }
        __syncthreads();
        if (s < 7) {
            int k0 = (s + 1) * 64;
#pragma unroll
            for (int q = 0; q < 8; ++q) {
                f[q] = *(const float4*)(aP + k0 + q * 4);
                g[q] = *(const float4*)(bP + k0 + q * 4);
            }
        }
#pragma unroll
        for (int kk = 0; kk < 2; ++kk) {
            bf16x8 av[4], bv[4];
            const int cb = kk * 64 + hi * 16;
#pragma unroll
            for (int t = 0; t < 4; ++t) {
                int arow = wr * 64 + t * 16 + ln15;
                av[t] = __builtin_bit_cast(bf16x8,
                        As16[arow * 8 + ((cb ^ ((arow & 7) << 4)) >> 4)]);
                int brow = wc * 64 + t * 16 + ln15;
                bv[t] = __builtin_bit_cast(bf16x8,
                        Bs16[brow * 8 + ((cb ^ ((brow & 7) << 4)) >> 4)]);
            }
#pragma unroll
            for (int i = 0; i < 4; ++i)
#pragma unroll
                for (int j = 0; j < 4; ++j)
                    acc[i][j] = __builtin_amdgcn_mfma_f32_16x16x32_bf16(
                        av[i], bv[j], acc[i][j], 0, 0, 0);
        }
        __syncthreads();
    }
    float rpv[4];
#pragma unroll
    for (int j = 0; j < 4; ++j) rpv[j] = rp[bn + wc * 64 + j * 16 + ln15];
#pragma unroll
    for (int i = 0; i < 4; ++i) {
#pragma unroll
        for (int rr = 0; rr < 4; ++rr) {
            int row = bm + wr * 64 + i * 16 + hi * 4 + rr;
            float rzv = rz[row];
#pragma unroll
            for (int j = 0; j < 4; ++j) {
                int col = bn + wc * 64 + j * 16 + ln15;
                sim[(size_t)row * Pn + col] = acc[i][j][rr] * rzv * rpv[j];
            }
        }
    }
}

__global__ __launch_bounds__(256) void topk_refine(const float* __restrict__ sim,
        const float* __restrict__ Z, const float* __restrict__ Pm,
        const float* __restrict__ rz, const float* __restrict__ rp,
        float* __restrict__ oidx, float* __restrict__ oval, int Pn) {
    int row = blockIdx.x * 4 + (threadIdx.x >> 6);
    int lane = threadIdx.x & 63;
    const float* rptr = sim + (size_t)row * Pn;

    float v[8]; int ix[8];
#pragma unroll
    for (int j = 0; j < 8; ++j) { v[j] = -FLT_MAX; ix[j] = -1; }

    const int iters = Pn >> 8;
    for (int t = 0; t < iters; ++t) {
        int base = t * 256 + lane * 4;
        float4 q = *(const float4*)(rptr + base);
        float vals[4] = {q.x, q.y, q.z, q.w};
#pragma unroll
        for (int e = 0; e < 4; ++e) {
            float val = vals[e];
            if (val > v[7]) {
                int idx = base + e;
                int pos = 7;
#pragma unroll
                for (int j = 6; j >= 0; --j) {
                    if (val > v[j]) { v[j+1] = v[j]; ix[j+1] = ix[j]; pos = j; }
                }
                v[pos] = val; ix[pos] = idx;
            }
        }
    }

    int cand[8];
#pragma unroll
    for (int k = 0; k < 8; ++k) {
        float bv = v[0]; int bi2 = ix[0];
#pragma unroll
        for (int off = 32; off; off >>= 1) {
            float ov = __shfl_xor(bv, off);
            int oi = __shfl_xor(bi2, off);
            if (ov > bv || (ov == bv && oi >= 0 && (unsigned)oi < (unsigned)bi2)) {
                bv = ov; bi2 = oi;
            }
        }
        cand[k] = bi2;
        if (bi2 == ix[0]) {
#pragma unroll
            for (int j = 0; j < 7; ++j) { v[j] = v[j+1]; ix[j] = ix[j+1]; }
            v[7] = -FLT_MAX; ix[7] = -1;
        }
    }

    float zv[8];
    const float* zrow = Z + (size_t)row * D_DIM + lane * 8;
#pragma unroll
    for (int j = 0; j < 8; ++j) zv[j] = zrow[j];
    float rzv = rz[row];

    float ex[8];
#pragma unroll
    for (int c = 0; c < 8; ++c) {
        int idx = cand[c];
        const float* prow = Pm + (size_t)idx * D_DIM + lane * 8;
        float s = 0.f;
#pragma unroll
        for (int j = 0; j < 8; ++j) s += zv[j] * prow[j];
#pragma unroll
        for (int off = 32; off; off >>= 1) s += __shfl_xor(s, off);
        ex[c] = s * rzv * rp[idx];
    }

    bool used[8] = {};
#pragma unroll
    for (int k = 0; k < 3; ++k) {
        float bv = -FLT_MAX; int bi2 = Pn; int bc = 0;
#pragma unroll
        for (int c = 0; c < 8; ++c) {
            if (!used[c] && (ex[c] > bv || (ex[c] == bv && cand[c] < bi2))) {
                bv = ex[c]; bi2 = cand[c]; bc = c;
            }
        }
        used[bc] = true;
        if (lane == 0) {
            oidx[(size_t)row * 3 + k] = (float)bi2;
            oval[(size_t)row * 3 + k] = bv;
        }
    }
}

extern "C" void kernel_launch(void* const* d_in, const int* in_sizes, int n_in,
                              void* d_out, int out_size, void* d_ws, size_t ws_size,
                              hipStream_t stream) {
    const float* Z  = (const float*)d_in[0];   // [B, 512]
    const float* Pm = (const float*)d_in[1];   // [P, 512]
    const int B  = in_sizes[0] / D_DIM;        // 8192
    const int Pn = in_sizes[1] / D_DIM;        // 32768

    float* sim  = (float*)d_out;
    float* oidx = sim + (size_t)B * Pn;
    float* oval = oidx + (size_t)B * 3;

    float* rz = (float*)d_ws;
    float* rp = rz + B;
    unsigned short* Zb = (unsigned short*)(rp + Pn);
    unsigned short* Pb = Zb + (size_t)B * D_DIM;
    uint2* part = (uint2*)(Pb + (size_t)Pn * D_DIM);

    const size_t NB = (size_t)Pn / 128;
    const size_t need_bf16  = (size_t)(B + Pn) * 4 + (size_t)(B + Pn) * D_DIM * 2;
    const size_t need_fused = need_bf16 + (size_t)B * NB * 4 * sizeof(uint2);

    dim3 grid((B / 128) * (Pn / 128));

    if (ws_size >= need_fused) {
        convert_norm_kernel<<<B / 4, 256, 0, stream>>>(Z, Zb, rz, B);
        convert_norm_kernel<<<Pn / 4, 256, 0, stream>>>(Pm, Pb, rp, Pn);
        gemm_lds_bf16<true><<<grid, 256, 0, stream>>>(Zb, Pb, sim, part, Pn);
        topk_reduce<<<B / 4, 256, 0, stream>>>(part, Z, Pm, rz, rp, oidx, oval, Pn);
    } else if (ws_size >= need_bf16) {
        convert_norm_kernel<<<B / 4, 256, 0, stream>>>(Z, Zb, rz, B);
        convert_norm_kernel<<<Pn / 4, 256, 0, stream>>>(Pm, Pb, rp, Pn);
        gemm_lds_bf16<false><<<grid, 256, 0, stream>>>(Zb, Pb, sim, nullptr, Pn);
        topk_refine<<<B / 4, 256, 0, stream>>>(sim, Z, Pm, rz, rp, oidx, oval, Pn);
    } else {
        rnorm_kernel<<<B / 4, 256, 0, stream>>>(Z, rz, B);
        rnorm_kernel<<<Pn / 4, 256, 0, stream>>>(Pm, rp, Pn);
        gemm_bf16_sim<<<grid, 256, 0, stream>>>(Z, Pm, rz, rp, sim, Pn);
        topk_refine<<<B / 4, 256, 0, stream>>>(sim, Z, Pm, rz, rp, oidx, oval, Pn);
    }
}

// Round 6
// 695.619 us; speedup vs baseline: 1.1008x; 1.1008x over previous
//
#include <hip/hip_runtime.h>
#include <float.h>
#include <stdint.h>

#define D_DIM 512

typedef __attribute__((ext_vector_type(8))) short bf16x8;
typedef __attribute__((ext_vector_type(4))) float f32x4;

// async global->LDS, 16B per lane (linear LDS dest: wave base + lane*16)
#define GLD_LDS16(g, l)                                              \
    __builtin_amdgcn_global_load_lds(                                \
        (const __attribute__((address_space(1))) void*)(g),          \
        (__attribute__((address_space(3))) void*)(l), 16, 0, 0)

// round-half-up f32->bf16, pack two into one u32
__device__ __forceinline__ uint32_t pk_bf16(float a, float b) {
    uint32_t ua = __builtin_bit_cast(uint32_t, a) + 0x8000u;
    uint32_t ub = __builtin_bit_cast(uint32_t, b) + 0x8000u;
    return (ua >> 16) | (ub & 0xFFFF0000u);
}

// ---------------------------------------------------------------------------
// Per-row: r[row] = 1/max(||X[row]||,eps); Xb[row,:] = bf16(X[row,:] * r).
// ---------------------------------------------------------------------------
__global__ __launch_bounds__(256) void convert_norm_kernel(
        const float* __restrict__ X, unsigned short* __restrict__ Xb,
        float* __restrict__ r, int R) {
    int row = blockIdx.x * 4 + (threadIdx.x >> 6);
    if (row >= R) return;
    int lane = threadIdx.x & 63;
    const float* x = X + (size_t)row * D_DIM + lane * 8;
    float4 f0 = *(const float4*)(x);
    float4 f1 = *(const float4*)(x + 4);
    float s = f0.x*f0.x + f0.y*f0.y + f0.z*f0.z + f0.w*f0.w
            + f1.x*f1.x + f1.y*f1.y + f1.z*f1.z + f1.w*f1.w;
#pragma unroll
    for (int off = 32; off; off >>= 1) s += __shfl_xor(s, off);
    float rv = 1.0f / fmaxf(sqrtf(s), 1e-12f);
    if (lane == 0) r[row] = rv;
    uint4 w;
    w.x = pk_bf16(f0.x * rv, f0.y * rv);
    w.y = pk_bf16(f0.z * rv, f0.w * rv);
    w.z = pk_bf16(f1.x * rv, f1.y * rv);
    w.w = pk_bf16(f1.z * rv, f1.w * rv);
    *(uint4*)(Xb + (size_t)row * D_DIM + lane * 8) = w;
}

// ---------------------------------------------------------------------------
// bf16 GEMM, BK=32 double-buffered pipeline at 32 KB LDS (4 blocks/CU):
//   iter t: issue STAGE(t+1) -> vmcnt(4) -> s_barrier -> ds_read+16 MFMA(t)
//           -> s_barrier.  Next-tile loads stay in flight across the phase.
// 128x128 tile, 4 waves, 4x4 frags mfma_f32_16x16x32_bf16, 16 K-steps.
// FUSE epilogue: 4 phases (2 row-halves x 2 col-halves), T[64][68]+M=25.6KB
// aliased over staging LDS; per-row top-4 per 128-col tile -> part.
// ---------------------------------------------------------------------------
template <bool FUSE>
__global__ __launch_bounds__(256, 4) void gemm_lds_bf16(
        const unsigned short* __restrict__ Zb,
        const unsigned short* __restrict__ Pb,
        float* __restrict__ sim, uint2* __restrict__ part, int Pn) {
    __shared__ __align__(16) unsigned char SH[32768];
    uint4* S = (uint4*)SH;   // dbuf: [buf*1024 + (A:0..511 | B:512..1023)]

    int bi = blockIdx.x;
    int mb, nb;
    if (gridDim.x == 16384) {            // XCD band mapping (B=8192,P=32768)
        int xcd = bi & 7;
        int r = bi >> 3;
        mb = xcd * 8 + (r & 7);          // 0..63
        nb = r >> 3;                     // 0..255
    } else {
        nb = bi % (Pn / 128);
        mb = bi / (Pn / 128);
    }
    const int bm = mb * 128, bn = nb * 128;

    const int tid = threadIdx.x;
    const int lane = tid & 63;
    const int wid = tid >> 6;
    const int wr = wid >> 1, wc = wid & 1;
    const int ln15 = lane & 15, hi = lane >> 4;

    // staging: 2 issues of 256 lanes x 16B for A and for B per K-step (BK=32)
    const unsigned short* gA[2];
    const unsigned short* gB[2];
    int ldsIdx[2];
#pragma unroll
    for (int q = 0; q < 2; ++q) {
        int flat = q * 256 + tid;        // 16B-chunk id: row*4 + c
        int row = flat >> 2;
        int c = flat & 3;
        int cg = c ^ (row & 3);          // pre-swizzled global chunk
        gA[q] = Zb + (size_t)(bm + row) * D_DIM + cg * 8;
        gB[q] = Pb + (size_t)(bn + row) * D_DIM + cg * 8;
        ldsIdx[q] = flat;
    }

    f32x4 acc[4][4] = {};

    // prologue: stage K-tile 0 into buffer 0
#pragma unroll
    for (int q = 0; q < 2; ++q) {
        GLD_LDS16(gA[q], &S[ldsIdx[q]]);
        GLD_LDS16(gB[q], &S[512 + ldsIdx[q]]);
        gA[q] += 32;
        gB[q] += 32;
    }

    int cur = 0;
#pragma unroll 1
    for (int s8 = 0; s8 < 16; ++s8) {
        const int nxt = cur ^ 1;
        if (s8 < 15) {
            // issue next-tile loads; they fly through this MFMA phase
#pragma unroll
            for (int q = 0; q < 2; ++q) {
                GLD_LDS16(gA[q], &S[nxt * 1024 + ldsIdx[q]]);
                GLD_LDS16(gB[q], &S[nxt * 1024 + 512 + ldsIdx[q]]);
                gA[q] += 32;
                gB[q] += 32;
            }
            asm volatile("s_waitcnt vmcnt(4)" ::: "memory");  // tile-t landed
        } else {
            asm volatile("s_waitcnt vmcnt(0)" ::: "memory");
        }
        __builtin_amdgcn_s_barrier();
        __builtin_amdgcn_sched_barrier(0);

        const int sb = cur * 1024;
        __builtin_amdgcn_s_setprio(1);
        bf16x8 av[4], bv[4];
#pragma unroll
        for (int t = 0; t < 4; ++t) {
            int arow = wr * 64 + t * 16 + ln15;
            av[t] = __builtin_bit_cast(bf16x8,
                    S[sb + arow * 4 + (hi ^ (arow & 3))]);
            int brow = wc * 64 + t * 16 + ln15;
            bv[t] = __builtin_bit_cast(bf16x8,
                    S[sb + 512 + brow * 4 + (hi ^ (brow & 3))]);
        }
#pragma unroll
        for (int i = 0; i < 4; ++i)
#pragma unroll
            for (int j = 0; j < 4; ++j)
                acc[i][j] = __builtin_amdgcn_mfma_f32_16x16x32_bf16(
                    av[i], bv[j], acc[i][j], 0, 0, 0);
        __builtin_amdgcn_s_setprio(0);
        __builtin_amdgcn_sched_barrier(0);
        __builtin_amdgcn_s_barrier();     // safe to overwrite buf[cur]
        cur = nxt;
    }

    // sim write: C/D layout col=lane&15, row=(lane>>4)*4+reg
#pragma unroll
    for (int i = 0; i < 4; ++i) {
#pragma unroll
        for (int rr = 0; rr < 4; ++rr) {
            int row = bm + wr * 64 + i * 16 + hi * 4 + rr;
#pragma unroll
            for (int j = 0; j < 4; ++j) {
                int col = bn + wc * 64 + j * 16 + ln15;
                sim[(size_t)row * Pn + col] = acc[i][j][rr];
            }
        }
    }

    if constexpr (FUSE) {
        float* T = (float*)SH;               // [64 cols][68 rows-pad] = 17408 B
        uint2* M = (uint2*)(SH + 17408);     // [4 q][4 k][64 r]       =  8192 B
        const int NB = Pn >> 7;
        const int r = tid & 63;
        const int q = tid >> 6;
#pragma unroll 1
        for (int hf = 0; hf < 2; ++hf) {
            float rv[4]; int ri[4];
#pragma unroll
            for (int k = 0; k < 4; ++k) { rv[k] = -FLT_MAX; ri[k] = 0x7FFFFFFF; }
#pragma unroll 1
            for (int ch = 0; ch < 2; ++ch) {
                __syncthreads();             // T free (prev phase done reading)
                if (wr == hf && wc == ch) {
#pragma unroll
                    for (int i = 0; i < 4; ++i)
#pragma unroll
                        for (int j = 0; j < 4; ++j)
                            *(f32x4*)&T[(j * 16 + ln15) * 68 + i * 16 + hi * 4]
                                = acc[i][j];
                }
                __syncthreads();
                // scan: thread -> (row r, 16-col strip q) of this 64-col half
                float tv[4]; int ti[4];
#pragma unroll
                for (int k = 0; k < 4; ++k) { tv[k] = -FLT_MAX; ti[k] = 0x7FFFFFFF; }
#pragma unroll
                for (int c4 = 0; c4 < 16; c4 += 4) {
                    float e0 = T[(q * 16 + c4 + 0) * 68 + r];
                    float e1 = T[(q * 16 + c4 + 1) * 68 + r];
                    float e2 = T[(q * 16 + c4 + 2) * 68 + r];
                    float e3 = T[(q * 16 + c4 + 3) * 68 + r];
                    float mg = fmaxf(fmaxf(e0, e1), fmaxf(e2, e3));
                    if (mg > tv[3]) {   // rare-path gate
                        float ee[4] = {e0, e1, e2, e3};
#pragma unroll
                        for (int e = 0; e < 4; ++e) {
                            float val = ee[e];
                            if (val > tv[3]) {
                                int p = 3;
#pragma unroll
                                for (int j2 = 2; j2 >= 0; --j2)
                                    if (val > tv[j2]) { tv[j2+1] = tv[j2]; ti[j2+1] = ti[j2]; p = j2; }
                                tv[p] = val; ti[p] = bn + ch * 64 + q * 16 + c4 + e;
                            }
                        }
                    }
                }
#pragma unroll
                for (int k = 0; k < 4; ++k)
                    M[q * 256 + k * 64 + r] =
                        make_uint2(__builtin_bit_cast(uint32_t, tv[k]), (uint32_t)ti[k]);
                __syncthreads();
                if (tid < 64) {   // merge 4 strips into running row top-4
#pragma unroll
                    for (int qq = 0; qq < 4; ++qq)
#pragma unroll
                        for (int k = 0; k < 4; ++k) {
                            uint2 u = M[qq * 256 + k * 64 + tid];
                            float val = __builtin_bit_cast(float, u.x);
                            if (val > rv[3]) {
                                int p = 3;
#pragma unroll
                                for (int j2 = 2; j2 >= 0; --j2)
                                    if (val > rv[j2]) { rv[j2+1] = rv[j2]; ri[j2+1] = ri[j2]; p = j2; }
                                rv[p] = val; ri[p] = (int)u.y;
                            }
                        }
                }
            }
            if (tid < 64) {
                size_t o = ((size_t)(bm + hf * 64 + tid) * NB + nb) * 4;
#pragma unroll
                for (int k = 0; k < 4; ++k)
                    part[o + k] =
                        make_uint2(__builtin_bit_cast(uint32_t, rv[k]), (uint32_t)ri[k]);
            }
        }
    }
}

// ---------------------------------------------------------------------------
// Reduce partial candidates (NB*4 per row) -> noisy top-8 -> exact f32
// rerank -> top-3. One wave per row.
// ---------------------------------------------------------------------------
__global__ __launch_bounds__(256) void topk_reduce(const uint2* __restrict__ part,
        const float* __restrict__ Z, const float* __restrict__ Pm,
        const float* __restrict__ rz, const float* __restrict__ rp,
        float* __restrict__ oidx, float* __restrict__ oval, int Pn) {
    int row = blockIdx.x * 4 + (threadIdx.x >> 6);
    int lane = threadIdx.x & 63;
    const int NB = Pn >> 7;
    const uint2* pr = part + (size_t)row * NB * 4;

    float v[8]; int ix[8];
#pragma unroll
    for (int j = 0; j < 8; ++j) { v[j] = -FLT_MAX; ix[j] = -1; }

    const int total = NB * 4;
    for (int c = lane; c < total; c += 64) {
        uint2 u = pr[c];
        float val = __builtin_bit_cast(float, u.x);
        if (val > v[7]) {
            int idx = (int)u.y;
            int pos = 7;
#pragma unroll
            for (int j = 6; j >= 0; --j) {
                if (val > v[j]) { v[j+1] = v[j]; ix[j+1] = ix[j]; pos = j; }
            }
            v[pos] = val; ix[pos] = idx;
        }
    }

    int cand[8];
#pragma unroll
    for (int k = 0; k < 8; ++k) {
        float bv = v[0]; int bi2 = ix[0];
#pragma unroll
        for (int off = 32; off; off >>= 1) {
            float ov = __shfl_xor(bv, off);
            int oi = __shfl_xor(bi2, off);
            if (ov > bv || (ov == bv && oi >= 0 && (unsigned)oi < (unsigned)bi2)) {
                bv = ov; bi2 = oi;
            }
        }
        cand[k] = bi2;
        if (bi2 == ix[0]) {
#pragma unroll
            for (int j = 0; j < 7; ++j) { v[j] = v[j+1]; ix[j] = ix[j+1]; }
            v[7] = -FLT_MAX; ix[7] = -1;
        }
    }

    // exact f32 recompute of the 8 candidate similarities
    float zv[8];
    const float* zrow = Z + (size_t)row * D_DIM + lane * 8;
#pragma unroll
    for (int j = 0; j < 8; ++j) zv[j] = zrow[j];
    float rzv = rz[row];

    float ex[8];
#pragma unroll
    for (int c = 0; c < 8; ++c) {
        int idx = cand[c];
        const float* prow = Pm + (size_t)idx * D_DIM + lane * 8;
        float s = 0.f;
#pragma unroll
        for (int j = 0; j < 8; ++j) s += zv[j] * prow[j];
#pragma unroll
        for (int off = 32; off; off >>= 1) s += __shfl_xor(s, off);
        ex[c] = s * rzv * rp[idx];
    }

    bool used[8] = {};
#pragma unroll
    for (int k = 0; k < 3; ++k) {
        float bv = -FLT_MAX; int bi2 = Pn; int bc = 0;
#pragma unroll
        for (int c = 0; c < 8; ++c) {
            if (!used[c] && (ex[c] > bv || (ex[c] == bv && cand[c] < bi2))) {
                bv = ex[c]; bi2 = cand[c]; bc = c;
            }
        }
        used[bc] = true;
        if (lane == 0) {
            oidx[(size_t)row * 3 + k] = (float)bi2;
            oval[(size_t)row * 3 + k] = bv;
        }
    }
}

// ---------------------------------------------------------------------------
// Fallbacks (smaller ws): topk over sim, f32-input reg-staging GEMM.
// ---------------------------------------------------------------------------
__global__ __launch_bounds__(256) void rnorm_kernel(const float* __restrict__ X,
                                                    float* __restrict__ r, int R) {
    int row = blockIdx.x * 4 + (threadIdx.x >> 6);
    if (row >= R) return;
    int lane = threadIdx.x & 63;
    const float* x = X + (size_t)row * D_DIM;
    float s = 0.f;
#pragma unroll
    for (int t = 0; t < 2; ++t) {
        float4 v = *(const float4*)(x + (t * 64 + lane) * 4);
        s += v.x * v.x + v.y * v.y + v.z * v.z + v.w * v.w;
    }
#pragma unroll
    for (int off = 32; off; off >>= 1) s += __shfl_xor(s, off);
    if (lane == 0) r[row] = 1.0f / fmaxf(sqrtf(s), 1e-12f);
}

__global__ __launch_bounds__(256, 2) void gemm_bf16_sim(const float* __restrict__ Z,
        const float* __restrict__ Pm, const float* __restrict__ rz,
        const float* __restrict__ rp, float* __restrict__ sim, int Pn) {
    __shared__ uint4 As16[1024];
    __shared__ uint4 Bs16[1024];
    int bi = blockIdx.x;
    int mb, nb;
    if (gridDim.x == 16384) {
        int xcd = bi & 7;
        int r = bi >> 3;
        mb = xcd * 8 + (r & 7);
        nb = r >> 3;
    } else {
        nb = bi % (Pn / 128);
        mb = bi / (Pn / 128);
    }
    const int bm = mb * 128, bn = nb * 128;
    const int tid = threadIdx.x;
    const int srow = tid >> 1;
    const int half = tid & 1;
    const float* aP = Z  + (size_t)(bm + srow) * D_DIM + half * 32;
    const float* bP = Pm + (size_t)(bn + srow) * D_DIM + half * 32;
    const int lane = tid & 63;
    const int wid = tid >> 6;
    const int wr = wid >> 1, wc = wid & 1;
    const int ln15 = lane & 15, hi = lane >> 4;
    f32x4 acc[4][4] = {};
    float4 f[8], g[8];
#pragma unroll
    for (int q = 0; q < 8; ++q) {
        f[q] = *(const float4*)(aP + q * 4);
        g[q] = *(const float4*)(bP + q * 4);
    }
#pragma unroll 1
    for (int s = 0; s < 8; ++s) {
#pragma unroll
        for (int q8 = 0; q8 < 4; ++q8) {
            uint4 wa, wb;
            wa.x = pk_bf16(f[2*q8].x,   f[2*q8].y);
            wa.y = pk_bf16(f[2*q8].z,   f[2*q8].w);
            wa.z = pk_bf16(f[2*q8+1].x, f[2*q8+1].y);
            wa.w = pk_bf16(f[2*q8+1].z, f[2*q8+1].w);
            wb.x = pk_bf16(g[2*q8].x,   g[2*q8].y);
            wb.y = pk_bf16(g[2*q8].z,   g[2*q8].w);
            wb.z = pk_bf16(g[2*q8+1].x, g[2*q8+1].y);
            wb.w = pk_bf16(g[2*q8+1].z, g[2*q8+1].w);
            int colByte = half * 64 + q8 * 16;
            int idx = srow * 8 + ((colByte ^ ((srow & 7) << 4)) >> 4);
            As16[idx] = wa;
            Bs16[idx] = wb;
        }
        __syncthreads();
        if (s < 7) {
            int k0 = (s + 1) * 64;
#pragma unroll
            for (int q = 0; q < 8; ++q) {
                f[q] = *(const float4*)(aP + k0 + q * 4);
                g[q] = *(const float4*)(bP + k0 + q * 4);
            }
        }
#pragma unroll
        for (int kk = 0; kk < 2; ++kk) {
            bf16x8 av[4], bv[4];
            const int cb = kk * 64 + hi * 16;
#pragma unroll
            for (int t = 0; t < 4; ++t) {
                int arow = wr * 64 + t * 16 + ln15;
                av[t] = __builtin_bit_cast(bf16x8,
                        As16[arow * 8 + ((cb ^ ((arow & 7) << 4)) >> 4)]);
                int brow = wc * 64 + t * 16 + ln15;
                bv[t] = __builtin_bit_cast(bf16x8,
                        Bs16[brow * 8 + ((cb ^ ((brow & 7) << 4)) >> 4)]);
            }
#pragma unroll
            for (int i = 0; i < 4; ++i)
#pragma unroll
                for (int j = 0; j < 4; ++j)
                    acc[i][j] = __builtin_amdgcn_mfma_f32_16x16x32_bf16(
                        av[i], bv[j], acc[i][j], 0, 0, 0);
        }
        __syncthreads();
    }
    float rpv[4];
#pragma unroll
    for (int j = 0; j < 4; ++j) rpv[j] = rp[bn + wc * 64 + j * 16 + ln15];
#pragma unroll
    for (int i = 0; i < 4; ++i) {
#pragma unroll
        for (int rr = 0; rr < 4; ++rr) {
            int row = bm + wr * 64 + i * 16 + hi * 4 + rr;
            float rzv = rz[row];
#pragma unroll
            for (int j = 0; j < 4; ++j) {
                int col = bn + wc * 64 + j * 16 + ln15;
                sim[(size_t)row * Pn + col] = acc[i][j][rr] * rzv * rpv[j];
            }
        }
    }
}

__global__ __launch_bounds__(256) void topk_refine(const float* __restrict__ sim,
        const float* __restrict__ Z, const float* __restrict__ Pm,
        const float* __restrict__ rz, const float* __restrict__ rp,
        float* __restrict__ oidx, float* __restrict__ oval, int Pn) {
    int row = blockIdx.x * 4 + (threadIdx.x >> 6);
    int lane = threadIdx.x & 63;
    const float* rptr = sim + (size_t)row * Pn;

    float v[8]; int ix[8];
#pragma unroll
    for (int j = 0; j < 8; ++j) { v[j] = -FLT_MAX; ix[j] = -1; }

    const int iters = Pn >> 8;
    for (int t = 0; t < iters; ++t) {
        int base = t * 256 + lane * 4;
        float4 q = *(const float4*)(rptr + base);
        float vals[4] = {q.x, q.y, q.z, q.w};
#pragma unroll
        for (int e = 0; e < 4; ++e) {
            float val = vals[e];
            if (val > v[7]) {
                int idx = base + e;
                int pos = 7;
#pragma unroll
                for (int j = 6; j >= 0; --j) {
                    if (val > v[j]) { v[j+1] = v[j]; ix[j+1] = ix[j]; pos = j; }
                }
                v[pos] = val; ix[pos] = idx;
            }
        }
    }

    int cand[8];
#pragma unroll
    for (int k = 0; k < 8; ++k) {
        float bv = v[0]; int bi2 = ix[0];
#pragma unroll
        for (int off = 32; off; off >>= 1) {
            float ov = __shfl_xor(bv, off);
            int oi = __shfl_xor(bi2, off);
            if (ov > bv || (ov == bv && oi >= 0 && (unsigned)oi < (unsigned)bi2)) {
                bv = ov; bi2 = oi;
            }
        }
        cand[k] = bi2;
        if (bi2 == ix[0]) {
#pragma unroll
            for (int j = 0; j < 7; ++j) { v[j] = v[j+1]; ix[j] = ix[j+1]; }
            v[7] = -FLT_MAX; ix[7] = -1;
        }
    }

    float zv[8];
    const float* zrow = Z + (size_t)row * D_DIM + lane * 8;
#pragma unroll
    for (int j = 0; j < 8; ++j) zv[j] = zrow[j];
    float rzv = rz[row];

    float ex[8];
#pragma unroll
    for (int c = 0; c < 8; ++c) {
        int idx = cand[c];
        const float* prow = Pm + (size_t)idx * D_DIM + lane * 8;
        float s = 0.f;
#pragma unroll
        for (int j = 0; j < 8; ++j) s += zv[j] * prow[j];
#pragma unroll
        for (int off = 32; off; off >>= 1) s += __shfl_xor(s, off);
        ex[c] = s * rzv * rp[idx];
    }

    bool used[8] = {};
#pragma unroll
    for (int k = 0; k < 3; ++k) {
        float bv = -FLT_MAX; int bi2 = Pn; int bc = 0;
#pragma unroll
        for (int c = 0; c < 8; ++c) {
            if (!used[c] && (ex[c] > bv || (ex[c] == bv && cand[c] < bi2))) {
                bv = ex[c]; bi2 = cand[c]; bc = c;
            }
        }
        used[bc] = true;
        if (lane == 0) {
            oidx[(size_t)row * 3 + k] = (float)bi2;
            oval[(size_t)row * 3 + k] = bv;
        }
    }
}

extern "C" void kernel_launch(void* const* d_in, const int* in_sizes, int n_in,
                              void* d_out, int out_size, void* d_ws, size_t ws_size,
                              hipStream_t stream) {
    const float* Z  = (const float*)d_in[0];   // [B, 512]
    const float* Pm = (const float*)d_in[1];   // [P, 512]
    const int B  = in_sizes[0] / D_DIM;        // 8192
    const int Pn = in_sizes[1] / D_DIM;        // 32768

    float* sim  = (float*)d_out;
    float* oidx = sim + (size_t)B * Pn;
    float* oval = oidx + (size_t)B * 3;

    float* rz = (float*)d_ws;
    float* rp = rz + B;
    unsigned short* Zb = (unsigned short*)(rp + Pn);
    unsigned short* Pb = Zb + (size_t)B * D_DIM;
    uint2* part = (uint2*)(Pb + (size_t)Pn * D_DIM);

    const size_t NB = (size_t)Pn / 128;
    const size_t need_bf16  = (size_t)(B + Pn) * 4 + (size_t)(B + Pn) * D_DIM * 2;
    const size_t need_fused = need_bf16 + (size_t)B * NB * 4 * sizeof(uint2);

    dim3 grid((B / 128) * (Pn / 128));

    if (ws_size >= need_fused) {
        convert_norm_kernel<<<B / 4, 256, 0, stream>>>(Z, Zb, rz, B);
        convert_norm_kernel<<<Pn / 4, 256, 0, stream>>>(Pm, Pb, rp, Pn);
        gemm_lds_bf16<true><<<grid, 256, 0, stream>>>(Zb, Pb, sim, part, Pn);
        topk_reduce<<<B / 4, 256, 0, stream>>>(part, Z, Pm, rz, rp, oidx, oval, Pn);
    } else if (ws_size >= need_bf16) {
        convert_norm_kernel<<<B / 4, 256, 0, stream>>>(Z, Zb, rz, B);
        convert_norm_kernel<<<Pn / 4, 256, 0, stream>>>(Pm, Pb, rp, Pn);
        gemm_lds_bf16<false><<<grid, 256, 0, stream>>>(Zb, Pb, sim, nullptr, Pn);
        topk_refine<<<B / 4, 256, 0, stream>>>(sim, Z, Pm, rz, rp, oidx, oval, Pn);
    } else {
        rnorm_kernel<<<B / 4, 256, 0, stream>>>(Z, rz, B);
        rnorm_kernel<<<Pn / 4, 256, 0, stream>>>(Pm, rp, Pn);
        gemm_bf16_sim<<<grid, 256, 0, stream>>>(Z, Pm, rz, rp, sim, Pn);
        topk_refine<<<B / 4, 256, 0, stream>>>(sim, Z, Pm, rz, rp, oidx, oval, Pn);
    }
}